// Round 1
// baseline (61.511 us; speedup 1.0000x reference)
//
#include <hip/hip_runtime.h>

// Cox NLL over N=16384:
//   risk[i] = cumsum(exp(pred))[i]  (inclusive)
//   cost = -(sum((pred - log(risk)) * yevent) / max(sum(yevent), 1))
// Single-block scan: 1024 threads x 16 contiguous elems each.

#define NLL_N     16384
#define NLL_BLOCK 1024
#define NLL_PT    16   // elements per thread = N / BLOCK

__global__ __launch_bounds__(NLL_BLOCK) void nll_kernel(
    const float* __restrict__ pred,
    const float* __restrict__ label,
    float* __restrict__ out)
{
    const int tid  = threadIdx.x;
    const int lane = tid & 63;
    const int wave = tid >> 6;   // 0..15

    // ---- load 16 contiguous preds (4 x float4) ----
    float p[NLL_PT];
    const float4* p4 = (const float4*)pred;
    #pragma unroll
    for (int v = 0; v < 4; ++v) {
        float4 x = p4[tid * 4 + v];
        p[v*4+0] = x.x; p[v*4+1] = x.y; p[v*4+2] = x.z; p[v*4+3] = x.w;
    }
    // ---- load yevent for my 16 rows: label is (N,2) interleaved -> 8 x float4 ----
    float ev[NLL_PT];
    const float4* l4 = (const float4*)label;
    #pragma unroll
    for (int v = 0; v < 8; ++v) {
        float4 x = l4[tid * 8 + v];
        ev[v*2+0] = x.y;   // row 2v   yevent
        ev[v*2+1] = x.w;   // row 2v+1 yevent
    }

    // ---- per-thread inclusive prefix of exp(pred) ----
    float pref[NLL_PT];
    float run = 0.f;
    #pragma unroll
    for (int i = 0; i < NLL_PT; ++i) { run += __expf(p[i]); pref[i] = run; }

    // ---- wave-level inclusive scan of thread totals ----
    float inc = run;
    #pragma unroll
    for (int off = 1; off < 64; off <<= 1) {
        float t = __shfl_up(inc, off, 64);
        if (lane >= off) inc += t;
    }
    __shared__ float wsum[16];
    __shared__ float wexc[16];
    if (lane == 63) wsum[wave] = inc;
    __syncthreads();

    // ---- scan the 16 wave totals (whole wave 0 active to keep shuffles uniform) ----
    if (wave == 0) {
        float x = (lane < 16) ? wsum[lane] : 0.f;
        #pragma unroll
        for (int off = 1; off < 16; off <<= 1) {
            float t = __shfl_up(x, off, 64);
            if (lane >= off) x += t;
        }
        if (lane < 16) wexc[lane] = x - wsum[lane];  // exclusive wave prefix
    }
    __syncthreads();

    const float base = wexc[wave] + (inc - run);  // exclusive prefix for this thread

    // ---- fused epilogue: masked diff-sum and event count ----
    float sd = 0.f, se = 0.f;
    #pragma unroll
    for (int i = 0; i < NLL_PT; ++i) {
        float risk = base + pref[i];
        sd = fmaf(ev[i], p[i] - __logf(risk), sd);
        se += ev[i];
    }

    // ---- block reduction ----
    #pragma unroll
    for (int off = 32; off > 0; off >>= 1) {
        sd += __shfl_down(sd, off, 64);
        se += __shfl_down(se, off, 64);
    }
    __shared__ float rd[16], re[16];
    if (lane == 0) { rd[wave] = sd; re[wave] = se; }
    __syncthreads();
    if (tid == 0) {
        float d = 0.f, e = 0.f;
        #pragma unroll
        for (int w = 0; w < 16; ++w) { d += rd[w]; e += re[w]; }
        out[1] = e;                                      // n_observed
        out[0] = (e == 0.f) ? 0.f : -(d / fmaxf(e, 1.f)); // cost
    }
}

extern "C" void kernel_launch(void* const* d_in, const int* in_sizes, int n_in,
                              void* d_out, int out_size, void* d_ws, size_t ws_size,
                              hipStream_t stream) {
    const float* pred  = (const float*)d_in[0];   // (N,1) float32
    const float* label = (const float*)d_in[1];   // (N,2) float32
    float* out = (float*)d_out;                   // [cost, n_observed]
    (void)in_sizes; (void)n_in; (void)out_size; (void)d_ws; (void)ws_size;
    nll_kernel<<<1, NLL_BLOCK, 0, stream>>>(pred, label, out);
}